// Round 12
// baseline (304.472 us; speedup 1.0000x reference)
//
#include <hip/hip_runtime.h>

#define KP 32
#define NQg 16384
#define CD 512
#define HC 256
#define NS 3

typedef __attribute__((ext_vector_type(8))) short short8;
typedef __attribute__((ext_vector_type(4))) short short4_t;
typedef __attribute__((ext_vector_type(8))) __bf16 bf16x8;
typedef __attribute__((ext_vector_type(4))) float floatx4;

union S8B8 { short8 s; bf16x8 b; };

__device__ __forceinline__ short f2bf(float f) {
    union { float f; unsigned u; } v; v.f = f;
    unsigned r = v.u + 0x7fffu + ((v.u >> 16) & 1u);   // RNE
    return (short)(r >> 16);
}
__device__ __forceinline__ float bf2f(short s) {
    union { unsigned u; float f; } v; v.u = ((unsigned)(unsigned short)s) << 16;
    return v.f;
}
__device__ __forceinline__ float bflo(unsigned u) { return __uint_as_float(u << 16); }
__device__ __forceinline__ float bfhi(unsigned u) { return __uint_as_float(u & 0xffff0000u); }

// ================ k_A: softmax | packs | qf->bf16 | zeros (R11 verbatim) ================
__global__ __launch_bounds__(256) void k_A(const float* __restrict__ qd,
                                           const float* __restrict__ W1, const float* __restrict__ W2,
                                           const float* __restrict__ Wc1, const float* __restrict__ proto,
                                           const float* __restrict__ qf,
                                           short* __restrict__ softT,
                                           short* __restrict__ W1p, short* __restrict__ W2p,
                                           short* __restrict__ wqp, float* __restrict__ refined,
                                           short* __restrict__ qf2b, float* __restrict__ wmean,
                                           int* __restrict__ bar, float* __restrict__ dout) {
    int tid = threadIdx.x;
    int bid = blockIdx.x;
    if (bid < 64) {
        int q = bid * 256 + tid;
        float d[32];
        const float4* p = (const float4*)(qd + (size_t)q * 32);
#pragma unroll
        for (int j = 0; j < 8; j++) {
            float4 v = p[j];
            d[4 * j] = v.x; d[4 * j + 1] = v.y; d[4 * j + 2] = v.z; d[4 * j + 3] = v.w;
        }
#pragma unroll
        for (int s = 0; s < 3; s++) {
            float inv = -1.0f / (float)(s + 1);
            float e[32];
            float sum = 0.f;
#pragma unroll
            for (int k = 0; k < 32; k++) { e[k] = __expf(d[k] * inv); sum += e[k]; }
            float r = 1.0f / sum;
#pragma unroll
            for (int k = 0; k < 32; k++)
                softT[(size_t)(s * 32 + k) * NQg + q] = f2bf(e[k] * r);
        }
        return;
    }
    if (bid < 3712) {
        if (bid == 64) {
            if (tid < 32) dout[16384 + tid] = 0.f;
            else if (tid < 40) bar[tid - 32] = 0;
        }
        int idx = (bid - 64) * 256 + tid;   // < 933888
        if (idx < 524288) {
            int k = idx >> 9, n = idx & 511;
            W1p[((size_t)(k >> 3) * 512 + n) * 8 + (k & 7)] = f2bf(W1[idx]);
        } else if (idx < 786432) {
            int j = idx - 524288;
            int k = j >> 9, n = j & 511;
            W2p[((size_t)(k >> 3) * 512 + n) * 8 + (k & 7)] = f2bf(W2[j]);
        } else if (idx < 917504) {
            int j = idx - 786432;
            int k = j >> 8, n = j & 255;
            wqp[((size_t)(k >> 3) * 256 + n) * 8 + (k & 7)] = f2bf(Wc1[(size_t)(512 + k) * 256 + n]);
        } else {
            int j = idx - 917504;
            refined[j] = proto[j];
        }
        return;
    }
    if (bid < 3904) {
        int idx = (bid - 3712) * 256 + tid;   // < 49152
        wmean[idx] = 0.f;
        return;
    }
    {
        int j = (bid - 3904) * 256 + tid;     // < 2,097,152 ; 4 elems each
        float4 v = *(const float4*)&qf[(size_t)j * 4];
        short4_t o;
        o[0] = f2bf(v.x); o[1] = f2bf(v.y); o[2] = f2bf(v.z); o[3] = f2bf(v.w);
        *(short4_t*)&qf2b[(size_t)j * 4] = o;
    }
}

// ================ k_B: 0..255 wmean | 256..511 hq | 512..607 wsuminv | 608..639 hpb (R11 verbatim) ================
__global__ __launch_bounds__(256) void k_B(const short* __restrict__ qf2b,
                                           const short* __restrict__ softT,
                                           const short* __restrict__ wqp,
                                           float* __restrict__ wmean,
                                           short* __restrict__ hq_g,
                                           float* __restrict__ wsuminv,
                                           const float* __restrict__ proto,
                                           const float* __restrict__ Wc1,
                                           const float* __restrict__ bc1,
                                           float* __restrict__ hpb) {
    __shared__ short B_lds[128 * 40];
    int tid = threadIdx.x;
    int lane = tid & 63, w = tid >> 6;
    int ml = lane & 15, q8 = lane >> 4;

    if (blockIdx.x < 256) {
        int kc = blockIdx.x >> 2, ns = blockIdx.x & 3;
        int c0 = ns * 128;
        int qbase0 = kc * 256;
        int c_l = 2 * lane;
        int q_l = 8 * w;

        floatx4 acc[6][2];
#pragma unroll
        for (int mt = 0; mt < 6; mt++)
#pragma unroll
            for (int nt = 0; nt < 2; nt++) acc[mt][nt] = (floatx4){0.f, 0.f, 0.f, 0.f};

        for (int step = 0; step < 8; step++) {
            int qb = qbase0 + step * 32;
            short8 sA, sB;
#pragma unroll
            for (int i = 0; i < 8; i++) {
                unsigned u = *(const unsigned*)&qf2b[(size_t)(qb + q_l + i) * 512 + c0 + c_l];
                sA[i] = (short)(u & 0xffffu);
                sB[i] = (short)(u >> 16);
            }
            __syncthreads();
            *(short8*)&B_lds[c_l * 40 + q_l] = sA;
            *(short8*)&B_lds[(c_l + 1) * 40 + q_l] = sB;
            S8B8 a[6];
#pragma unroll
            for (int mt = 0; mt < 6; mt++)
                a[mt].s = *(const short8*)&softT[(size_t)(mt * 16 + ml) * NQg + qb + q8 * 8];
            __syncthreads();
#pragma unroll
            for (int nt = 0; nt < 2; nt++) {
                S8B8 b; b.s = *(short8*)&B_lds[(w * 32 + nt * 16 + ml) * 40 + q8 * 8];
#pragma unroll
                for (int mt = 0; mt < 6; mt++)
                    acc[mt][nt] = __builtin_amdgcn_mfma_f32_16x16x32_bf16(a[mt].b, b.b, acc[mt][nt], 0, 0, 0);
            }
        }
#pragma unroll
        for (int mt = 0; mt < 6; mt++) {
#pragma unroll
            for (int nt = 0; nt < 2; nt++) {
                int c = c0 + w * 32 + nt * 16 + ml;
#pragma unroll
                for (int r = 0; r < 4; r++) {
                    int m = mt * 16 + q8 * 4 + r;
                    atomicAdd(&wmean[(size_t)m * 512 + c], acc[mt][nt][r]);
                }
            }
        }
    } else if (blockIdx.x < 512) {
        int m0 = (blockIdx.x - 256) * 64;
        int n0 = w * 64;
        floatx4 acc[4][4];
#pragma unroll
        for (int mt = 0; mt < 4; mt++)
#pragma unroll
            for (int nt = 0; nt < 4; nt++) acc[mt][nt] = (floatx4){0.f, 0.f, 0.f, 0.f};

#pragma unroll 4
        for (int kc = 0; kc < 512; kc += 32) {
            S8B8 a[4], b[4];
#pragma unroll
            for (int mt = 0; mt < 4; mt++)
                a[mt].s = *(const short8*)&qf2b[(size_t)(m0 + mt * 16 + ml) * 512 + kc + q8 * 8];
#pragma unroll
            for (int nt = 0; nt < 4; nt++)
                b[nt].s = *(const short8*)&wqp[((size_t)((kc >> 3) + q8) * 256 + n0 + nt * 16 + ml) * 8];
#pragma unroll
            for (int mt = 0; mt < 4; mt++)
#pragma unroll
                for (int nt = 0; nt < 4; nt++)
                    acc[mt][nt] = __builtin_amdgcn_mfma_f32_16x16x32_bf16(a[mt].b, b[nt].b, acc[mt][nt], 0, 0, 0);
        }
#pragma unroll
        for (int mt = 0; mt < 4; mt++)
#pragma unroll
            for (int nt = 0; nt < 4; nt++) {
                int col = n0 + nt * 16 + ml;
#pragma unroll
                for (int r = 0; r < 4; r++) {
                    int row = m0 + mt * 16 + q8 * 4 + r;
                    hq_g[(size_t)row * 256 + col] = f2bf(acc[mt][nt][r]);
                }
            }
    } else if (blockIdx.x < 608) {
        float* red = (float*)B_lds;   // 256 f, reuse LDS
        int sk = blockIdx.x - 512;
        const short* row = softT + (size_t)sk * NQg;
        float s = 0.f;
#pragma unroll
        for (int j = 0; j < 8; j++) {
            short8 v = *(const short8*)&row[j * 2048 + tid * 8];
#pragma unroll
            for (int i = 0; i < 8; i++) s += bf2f(v[i]);
        }
        red[tid] = s;
        __syncthreads();
        for (int off = 128; off > 0; off >>= 1) {
            if (tid < off) red[tid] += red[tid + off];
            __syncthreads();
        }
        if (tid == 0) wsuminv[sk] = 1.0f / fmaxf(red[0], 1e-6f);
    } else {
        // ---- hpb: 4 independent accumulators + unroll (R11 verbatim) ----
        int r = blockIdx.x - 608;
        const float* pr = proto + r * 512;
        const float* wc = Wc1 + tid;
        float a0 = 0.f, a1 = 0.f, a2 = 0.f, a3 = 0.f;
#pragma unroll 4
        for (int i = 0; i < 512; i += 4) {
            float4 p4 = *(const float4*)&pr[i];
            float w0 = wc[(size_t)i * 256];
            float w1 = wc[(size_t)(i + 1) * 256];
            float w2 = wc[(size_t)(i + 2) * 256];
            float w3 = wc[(size_t)(i + 3) * 256];
            a0 += p4.x * w0;
            a1 += p4.y * w1;
            a2 += p4.z * w2;
            a3 += p4.w * w3;
        }
        hpb[r * 256 + tid] = bc1[tid] + ((a0 + a1) + (a2 + a3));
    }
}

// ================ k_D: block 0 = single-block MLP (no global barriers) | 1..1024 confidence ================
// LDS union: MLP hb[32][520] bf16 = 33,280 B ; conf = 26,752 B -> smem[8320] f
__global__ __launch_bounds__(256) void k_D(const float* __restrict__ wmean,
                                           const float* __restrict__ wsuminv,
                                           const short* __restrict__ W1p,
                                           const float* __restrict__ b1,
                                           const short* __restrict__ W2p,
                                           const float* __restrict__ b2,
                                           float* __restrict__ refined,
                                           const short* __restrict__ hq_g,
                                           const float* __restrict__ hpb,
                                           const float* __restrict__ Wc2,
                                           const float* __restrict__ bc2p,
                                           float* __restrict__ dout) {
    __shared__ float smem[8320];   // 33,280 B
    int tid = threadIdx.x, lane = tid & 63, w = tid >> 6;
    int ml = lane & 15, q8 = lane >> 4;

    if (blockIdx.x == 0) {
        // ---- fused 3-step MLP on ONE block: waves split N (128 cols each), full K per wave ----
        short* hb_lds = (short*)smem;          // [32][520] bf16
        int nbase = w * 128;
        for (int s = 0; s < 3; s++) {
            float iv0 = wsuminv[s * 32 + ml];
            float iv1 = wsuminv[s * 32 + 16 + ml];
            const float* wmn = wmean + (size_t)s * 32 * 512;
            // ---- layer 1: h = relu(concat @ W1 + b1), K=1024 ----
            floatx4 acc[2][8];
#pragma unroll
            for (int mt = 0; mt < 2; mt++)
#pragma unroll
                for (int nt = 0; nt < 8; nt++) acc[mt][nt] = (floatx4){0.f, 0.f, 0.f, 0.f};
#pragma unroll 4
            for (int kk = 0; kk < 32; kk++) {
                int kgl = kk * 32 + q8 * 8;           // global concat-k for this lane
                S8B8 a[2];
                if (kk < 16) {
#pragma unroll
                    for (int mt = 0; mt < 2; mt++) {
                        const float* p = &refined[(size_t)(mt * 16 + ml) * 512 + kgl];
                        float4 f0 = *(const float4*)p;
                        float4 f1 = *(const float4*)(p + 4);
                        short8 t;
                        t[0] = f2bf(f0.x); t[1] = f2bf(f0.y); t[2] = f2bf(f0.z); t[3] = f2bf(f0.w);
                        t[4] = f2bf(f1.x); t[5] = f2bf(f1.y); t[6] = f2bf(f1.z); t[7] = f2bf(f1.w);
                        a[mt].s = t;
                    }
                } else {
                    int kw = kgl - 512;
#pragma unroll
                    for (int mt = 0; mt < 2; mt++) {
                        float sc = mt ? iv1 : iv0;
                        const float* p = &wmn[(size_t)(mt * 16 + ml) * 512 + kw];
                        float4 f0 = *(const float4*)p;
                        float4 f1 = *(const float4*)(p + 4);
                        short8 t;
                        t[0] = f2bf(f0.x * sc); t[1] = f2bf(f0.y * sc);
                        t[2] = f2bf(f0.z * sc); t[3] = f2bf(f0.w * sc);
                        t[4] = f2bf(f1.x * sc); t[5] = f2bf(f1.y * sc);
                        t[6] = f2bf(f1.z * sc); t[7] = f2bf(f1.w * sc);
                        a[mt].s = t;
                    }
                }
#pragma unroll
                for (int nt = 0; nt < 8; nt++) {
                    int n = nbase + nt * 16 + ml;
                    S8B8 b; b.s = *(const short8*)&W1p[((size_t)(kgl >> 3) * 512 + n) * 8];
#pragma unroll
                    for (int mt = 0; mt < 2; mt++)
                        acc[mt][nt] = __builtin_amdgcn_mfma_f32_16x16x32_bf16(a[mt].b, b.b, acc[mt][nt], 0, 0, 0);
                }
            }
            // epilogue: bias+relu -> hb_lds (each wave owns full K -> no reduce)
            if (s > 0) __syncthreads();   // prior L2 hb reads done before overwrite
#pragma unroll
            for (int mt = 0; mt < 2; mt++)
#pragma unroll
                for (int nt = 0; nt < 8; nt++) {
                    int col = nbase + nt * 16 + ml;
                    float bv = b1[col];
#pragma unroll
                    for (int r = 0; r < 4; r++) {
                        int row = mt * 16 + q8 * 4 + r;
                        hb_lds[row * 520 + col] = f2bf(fmaxf(acc[mt][nt][r] + bv, 0.f));
                    }
                }
            __syncthreads();
            // ---- layer 2: refined += 0.1*(h @ W2 + b2), K=512 ----
            floatx4 acc2[2][8];
#pragma unroll
            for (int mt = 0; mt < 2; mt++)
#pragma unroll
                for (int nt = 0; nt < 8; nt++) acc2[mt][nt] = (floatx4){0.f, 0.f, 0.f, 0.f};
#pragma unroll 4
            for (int kk = 0; kk < 16; kk++) {
                int k0 = kk * 32 + q8 * 8;
                S8B8 a[2];
#pragma unroll
                for (int mt = 0; mt < 2; mt++)
                    a[mt].s = *(short8*)&hb_lds[(mt * 16 + ml) * 520 + k0];
#pragma unroll
                for (int nt = 0; nt < 8; nt++) {
                    int n = nbase + nt * 16 + ml;
                    S8B8 b; b.s = *(const short8*)&W2p[((size_t)(k0 >> 3) * 512 + n) * 8];
#pragma unroll
                    for (int mt = 0; mt < 2; mt++)
                        acc2[mt][nt] = __builtin_amdgcn_mfma_f32_16x16x32_bf16(a[mt].b, b.b, acc2[mt][nt], 0, 0, 0);
                }
            }
#pragma unroll
            for (int mt = 0; mt < 2; mt++)
#pragma unroll
                for (int nt = 0; nt < 8; nt++) {
                    int c = nbase + nt * 16 + ml;
                    float bv = b2[c];
#pragma unroll
                    for (int r = 0; r < 4; r++) {
                        int row = mt * 16 + q8 * 4 + r;
                        float val = refined[(size_t)row * 512 + c] + 0.1f * (acc2[mt][nt][r] + bv);
                        refined[(size_t)row * 512 + c] = val;
                        if (s == 2) dout[(size_t)row * 512 + c] = val;
                    }
                }
            __syncthreads();   // refined visible to all waves before next step's L1
        }
    } else {
        // ---- confidence (R11 verbatim): block = 16q; thread = 2k x 1q ----
        short* hq_lds = (short*)smem;                  // [16][280] s = 8960 B
        short* hp_s   = (short*)smem + 4480;           // [32][260] s = 16640 B
        float* wc2s   = smem + 6400;                   // 256 f
        float* confl  = smem + 6656;                   // 32 f
        int q0 = (blockIdx.x - 1) * 16;

        wc2s[tid] = Wc2[tid];
        if (tid < 32) confl[tid] = 0.f;
#pragma unroll
        for (int i = 0; i < 8; i++) {                  // hp: 2048 float4 -> bf16 short4
            int idx = i * 256 + tid;
            int r = idx >> 6, c = (idx & 63) * 4;
            float4 v = *(const float4*)&hpb[r * 256 + c];
            short4_t o;
            o[0] = f2bf(v.x); o[1] = f2bf(v.y); o[2] = f2bf(v.z); o[3] = f2bf(v.w);
            *(short4_t*)&hp_s[r * 260 + c] = o;
        }
        {
            const short* hqs = hq_g + (size_t)q0 * 256;
            int r = tid >> 4, c = (tid & 15) * 16;
            *(short8*)&hq_lds[r * 280 + c] = *(const short8*)&hqs[r * 256 + c];
            *(short8*)&hq_lds[r * 280 + c + 8] = *(const short8*)&hqs[r * 256 + c + 8];
        }
        __syncthreads();

        int q = tid & 15, kg = tid >> 4;
        int k0 = kg, k1 = kg + 16;
        float s0 = 0.f, s1 = 0.f;
        for (int h = 0; h < 256; h += 4) {
            uint2 hv = *(uint2*)&hq_lds[q * 280 + h];
            float f0 = bflo(hv.x), f1 = bfhi(hv.x), f2 = bflo(hv.y), f3 = bfhi(hv.y);
            uint2 u0 = *(uint2*)&hp_s[k0 * 260 + h];
            uint2 u1 = *(uint2*)&hp_s[k1 * 260 + h];
            float4 wv = *(float4*)&wc2s[h];
            s0 += fmaxf(bflo(u0.x) + f0, 0.f) * wv.x;
            s0 += fmaxf(bfhi(u0.x) + f1, 0.f) * wv.y;
            s0 += fmaxf(bflo(u0.y) + f2, 0.f) * wv.z;
            s0 += fmaxf(bfhi(u0.y) + f3, 0.f) * wv.w;
            s1 += fmaxf(bflo(u1.x) + f0, 0.f) * wv.x;
            s1 += fmaxf(bfhi(u1.x) + f1, 0.f) * wv.y;
            s1 += fmaxf(bflo(u1.y) + f2, 0.f) * wv.z;
            s1 += fmaxf(bfhi(u1.y) + f3, 0.f) * wv.w;
        }
        float bc2 = bc2p[0];
        float v0 = 1.f / (1.f + __expf(-(s0 + bc2)));
        float v1 = 1.f / (1.f + __expf(-(s1 + bc2)));
        atomicAdd(&confl[k0], v0);
        atomicAdd(&confl[k1], v1);
        __syncthreads();
        if (tid < 32) atomicAdd(&dout[16384 + tid], confl[tid] * (1.0f / 16384.0f));
    }
}

extern "C" void kernel_launch(void* const* d_in, const int* in_sizes, int n_in,
                              void* d_out, int out_size, void* d_ws, size_t ws_size,
                              hipStream_t stream) {
    const float* proto = (const float*)d_in[0];
    const float* qf    = (const float*)d_in[1];
    const float* qd    = (const float*)d_in[2];
    const float* W1    = (const float*)d_in[3];
    const float* b1    = (const float*)d_in[4];
    const float* W2    = (const float*)d_in[5];
    const float* b2    = (const float*)d_in[6];
    const float* Wc1   = (const float*)d_in[7];
    const float* bc1   = (const float*)d_in[8];
    const float* Wc2   = (const float*)d_in[9];
    const float* bc2   = (const float*)d_in[10];
    float* out = (float*)d_out;

    float* ws = (float*)d_ws;
    short* softT   = (short*)ws;                 // 1,572,864 s
    short* qf2b    = (short*)(ws + 786432);      // 8,388,608 s
    float* wmean   = ws + 4980736;               // 49,152 f (raw accumulator)
    float* refined = ws + 5029888;               // 16,384 f
    short* W1p     = (short*)(ws + 5054464);     // 524,288 s
    short* W2p     = (short*)(ws + 5316608);     // 262,144 s
    short* wqp     = (short*)(ws + 5447680);     // 131,072 s
    float* hpb     = ws + 5513216;               // 8,192 f
    int*   bar     = (int*)(ws + 5521408);       // 8 ints (unused by k_D now)
    float* wsuminv = ws + 5521416;               // 96 f
    short* hq      = (short*)(ws + 5521536);     // 4,194,304 s

    k_A<<<12096, 256, 0, stream>>>(qd, W1, W2, Wc1, proto, qf, softT, W1p, W2p, wqp,
                                   refined, qf2b, wmean, bar, out);
    k_B<<<640, 256, 0, stream>>>(qf2b, softT, wqp, wmean, hq, wsuminv, proto, Wc1, bc1, hpb);
    k_D<<<1025, 256, 0, stream>>>(wmean, wsuminv, W1p, b1, W2p, b2, refined,
                                  hq, hpb, Wc2, bc2, out);
}

// Round 13
// 170.727 us; speedup vs baseline: 1.7834x; 1.7834x over previous
//
#include <hip/hip_runtime.h>

#define KP 32
#define NQg 16384
#define CD 512
#define HC 256
#define NS 3

typedef __attribute__((ext_vector_type(8))) short short8;
typedef __attribute__((ext_vector_type(4))) short short4_t;
typedef __attribute__((ext_vector_type(8))) __bf16 bf16x8;
typedef __attribute__((ext_vector_type(4))) float floatx4;

union S8B8 { short8 s; bf16x8 b; };

__device__ __forceinline__ short f2bf(float f) {
    union { float f; unsigned u; } v; v.f = f;
    unsigned r = v.u + 0x7fffu + ((v.u >> 16) & 1u);   // RNE
    return (short)(r >> 16);
}
__device__ __forceinline__ float bf2f(short s) {
    union { unsigned u; float f; } v; v.u = ((unsigned)(unsigned short)s) << 16;
    return v.f;
}
__device__ __forceinline__ float bflo(unsigned u) { return __uint_as_float(u << 16); }
__device__ __forceinline__ float bfhi(unsigned u) { return __uint_as_float(u & 0xffff0000u); }

// ================ k_A: softmax | packs | qf->bf16 (4 groups/thread) | zeros ================
__global__ __launch_bounds__(256) void k_A(const float* __restrict__ qd,
                                           const float* __restrict__ W1, const float* __restrict__ W2,
                                           const float* __restrict__ Wc1, const float* __restrict__ proto,
                                           const float* __restrict__ qf,
                                           short* __restrict__ softT,
                                           short* __restrict__ W1p, short* __restrict__ W2p,
                                           short* __restrict__ wqp, float* __restrict__ refined,
                                           short* __restrict__ qf2b, float* __restrict__ wmean,
                                           int* __restrict__ bar, float* __restrict__ dout) {
    int tid = threadIdx.x;
    int bid = blockIdx.x;
    if (bid < 64) {
        int q = bid * 256 + tid;
        float d[32];
        const float4* p = (const float4*)(qd + (size_t)q * 32);
#pragma unroll
        for (int j = 0; j < 8; j++) {
            float4 v = p[j];
            d[4 * j] = v.x; d[4 * j + 1] = v.y; d[4 * j + 2] = v.z; d[4 * j + 3] = v.w;
        }
#pragma unroll
        for (int s = 0; s < 3; s++) {
            float inv = -1.0f / (float)(s + 1);
            float e[32];
            float sum = 0.f;
#pragma unroll
            for (int k = 0; k < 32; k++) { e[k] = __expf(d[k] * inv); sum += e[k]; }
            float r = 1.0f / sum;
#pragma unroll
            for (int k = 0; k < 32; k++)
                softT[(size_t)(s * 32 + k) * NQg + q] = f2bf(e[k] * r);
        }
        return;
    }
    if (bid < 3712) {
        if (bid == 64) {
            if (tid < 32) dout[16384 + tid] = 0.f;
            else if (tid < 40) bar[tid - 32] = 0;
        }
        int idx = (bid - 64) * 256 + tid;   // < 933888
        if (idx < 524288) {
            int k = idx >> 9, n = idx & 511;
            W1p[((size_t)(k >> 3) * 512 + n) * 8 + (k & 7)] = f2bf(W1[idx]);
        } else if (idx < 786432) {
            int j = idx - 524288;
            int k = j >> 9, n = j & 511;
            W2p[((size_t)(k >> 3) * 512 + n) * 8 + (k & 7)] = f2bf(W2[j]);
        } else if (idx < 917504) {
            int j = idx - 786432;
            int k = j >> 8, n = j & 255;
            wqp[((size_t)(k >> 3) * 256 + n) * 8 + (k & 7)] = f2bf(Wc1[(size_t)(512 + k) * 256 + n]);
        } else {
            int j = idx - 917504;
            refined[j] = proto[j];
        }
        return;
    }
    if (bid < 3904) {
        int idx = (bid - 3712) * 256 + tid;   // < 49152
        wmean[idx] = 0.f;
        return;
    }
    {
        // cast qf -> bf16: 2048 blocks x 4 coalesced float4-groups per thread
#pragma unroll
        for (int it = 0; it < 4; it++) {
            int j = (bid - 3904) * 1024 + it * 256 + tid;   // < 2,097,152
            float4 v = *(const float4*)&qf[(size_t)j * 4];
            short4_t o;
            o[0] = f2bf(v.x); o[1] = f2bf(v.y); o[2] = f2bf(v.z); o[3] = f2bf(v.w);
            *(short4_t*)&qf2b[(size_t)j * 4] = o;
        }
    }
}

// ================ k_B: 0..255 wmean | 256..511 hq | 512..607 wsuminv | 608..639 hpb (R11 verbatim) ================
__global__ __launch_bounds__(256) void k_B(const short* __restrict__ qf2b,
                                           const short* __restrict__ softT,
                                           const short* __restrict__ wqp,
                                           float* __restrict__ wmean,
                                           short* __restrict__ hq_g,
                                           float* __restrict__ wsuminv,
                                           const float* __restrict__ proto,
                                           const float* __restrict__ Wc1,
                                           const float* __restrict__ bc1,
                                           float* __restrict__ hpb) {
    __shared__ short B_lds[128 * 40];
    int tid = threadIdx.x;
    int lane = tid & 63, w = tid >> 6;
    int ml = lane & 15, q8 = lane >> 4;

    if (blockIdx.x < 256) {
        int kc = blockIdx.x >> 2, ns = blockIdx.x & 3;
        int c0 = ns * 128;
        int qbase0 = kc * 256;
        int c_l = 2 * lane;
        int q_l = 8 * w;

        floatx4 acc[6][2];
#pragma unroll
        for (int mt = 0; mt < 6; mt++)
#pragma unroll
            for (int nt = 0; nt < 2; nt++) acc[mt][nt] = (floatx4){0.f, 0.f, 0.f, 0.f};

        for (int step = 0; step < 8; step++) {
            int qb = qbase0 + step * 32;
            short8 sA, sB;
#pragma unroll
            for (int i = 0; i < 8; i++) {
                unsigned u = *(const unsigned*)&qf2b[(size_t)(qb + q_l + i) * 512 + c0 + c_l];
                sA[i] = (short)(u & 0xffffu);
                sB[i] = (short)(u >> 16);
            }
            __syncthreads();
            *(short8*)&B_lds[c_l * 40 + q_l] = sA;
            *(short8*)&B_lds[(c_l + 1) * 40 + q_l] = sB;
            S8B8 a[6];
#pragma unroll
            for (int mt = 0; mt < 6; mt++)
                a[mt].s = *(const short8*)&softT[(size_t)(mt * 16 + ml) * NQg + qb + q8 * 8];
            __syncthreads();
#pragma unroll
            for (int nt = 0; nt < 2; nt++) {
                S8B8 b; b.s = *(short8*)&B_lds[(w * 32 + nt * 16 + ml) * 40 + q8 * 8];
#pragma unroll
                for (int mt = 0; mt < 6; mt++)
                    acc[mt][nt] = __builtin_amdgcn_mfma_f32_16x16x32_bf16(a[mt].b, b.b, acc[mt][nt], 0, 0, 0);
            }
        }
#pragma unroll
        for (int mt = 0; mt < 6; mt++) {
#pragma unroll
            for (int nt = 0; nt < 2; nt++) {
                int c = c0 + w * 32 + nt * 16 + ml;
#pragma unroll
                for (int r = 0; r < 4; r++) {
                    int m = mt * 16 + q8 * 4 + r;
                    atomicAdd(&wmean[(size_t)m * 512 + c], acc[mt][nt][r]);
                }
            }
        }
    } else if (blockIdx.x < 512) {
        int m0 = (blockIdx.x - 256) * 64;
        int n0 = w * 64;
        floatx4 acc[4][4];
#pragma unroll
        for (int mt = 0; mt < 4; mt++)
#pragma unroll
            for (int nt = 0; nt < 4; nt++) acc[mt][nt] = (floatx4){0.f, 0.f, 0.f, 0.f};

#pragma unroll 4
        for (int kc = 0; kc < 512; kc += 32) {
            S8B8 a[4], b[4];
#pragma unroll
            for (int mt = 0; mt < 4; mt++)
                a[mt].s = *(const short8*)&qf2b[(size_t)(m0 + mt * 16 + ml) * 512 + kc + q8 * 8];
#pragma unroll
            for (int nt = 0; nt < 4; nt++)
                b[nt].s = *(const short8*)&wqp[((size_t)((kc >> 3) + q8) * 256 + n0 + nt * 16 + ml) * 8];
#pragma unroll
            for (int mt = 0; mt < 4; mt++)
#pragma unroll
                for (int nt = 0; nt < 4; nt++)
                    acc[mt][nt] = __builtin_amdgcn_mfma_f32_16x16x32_bf16(a[mt].b, b[nt].b, acc[mt][nt], 0, 0, 0);
        }
#pragma unroll
        for (int mt = 0; mt < 4; mt++)
#pragma unroll
            for (int nt = 0; nt < 4; nt++) {
                int col = n0 + nt * 16 + ml;
#pragma unroll
                for (int r = 0; r < 4; r++) {
                    int row = m0 + mt * 16 + q8 * 4 + r;
                    hq_g[(size_t)row * 256 + col] = f2bf(acc[mt][nt][r]);
                }
            }
    } else if (blockIdx.x < 608) {
        float* red = (float*)B_lds;   // 256 f, reuse LDS
        int sk = blockIdx.x - 512;
        const short* row = softT + (size_t)sk * NQg;
        float s = 0.f;
#pragma unroll
        for (int j = 0; j < 8; j++) {
            short8 v = *(const short8*)&row[j * 2048 + tid * 8];
#pragma unroll
            for (int i = 0; i < 8; i++) s += bf2f(v[i]);
        }
        red[tid] = s;
        __syncthreads();
        for (int off = 128; off > 0; off >>= 1) {
            if (tid < off) red[tid] += red[tid + off];
            __syncthreads();
        }
        if (tid == 0) wsuminv[sk] = 1.0f / fmaxf(red[0], 1e-6f);
    } else {
        // ---- hpb: 4 independent accumulators + unroll (R11 verbatim) ----
        int r = blockIdx.x - 608;
        const float* pr = proto + r * 512;
        const float* wc = Wc1 + tid;
        float a0 = 0.f, a1 = 0.f, a2 = 0.f, a3 = 0.f;
#pragma unroll 4
        for (int i = 0; i < 512; i += 4) {
            float4 p4 = *(const float4*)&pr[i];
            float w0 = wc[(size_t)i * 256];
            float w1 = wc[(size_t)(i + 1) * 256];
            float w2 = wc[(size_t)(i + 2) * 256];
            float w3 = wc[(size_t)(i + 3) * 256];
            a0 += p4.x * w0;
            a1 += p4.y * w1;
            a2 += p4.z * w2;
            a3 += p4.w * w3;
        }
        hpb[r * 256 + tid] = bc1[tid] + ((a0 + a1) + (a2 + a3));
    }
}

// ================ global spin barrier (16 co-resident blocks — PROVEN size, do not widen) ================
__device__ __forceinline__ void gbar(int* bar, int phase, int nblk) {
    __syncthreads();
    if (threadIdx.x == 0) {
        __threadfence();
        __hip_atomic_fetch_add(&bar[phase], 1, __ATOMIC_ACQ_REL, __HIP_MEMORY_SCOPE_AGENT);
        while (__hip_atomic_load(&bar[phase], __ATOMIC_ACQUIRE, __HIP_MEMORY_SCOPE_AGENT) < nblk)
            __builtin_amdgcn_s_sleep(1);
    }
    __syncthreads();
}

// ================ k_D: blocks 0..15 fused 3-step MLP | 16..1039 confidence (R11 verbatim) ================
__global__ __launch_bounds__(256) void k_D(const float* __restrict__ wmean,
                                           const float* __restrict__ wsuminv,
                                           const short* __restrict__ W1p,
                                           const float* __restrict__ b1,
                                           const short* __restrict__ W2p,
                                           const float* __restrict__ b2,
                                           float* __restrict__ refined,
                                           short* __restrict__ hb,
                                           int* __restrict__ bar,
                                           const short* __restrict__ hq_g,
                                           const float* __restrict__ hpb,
                                           const float* __restrict__ Wc2,
                                           const float* __restrict__ bc2p,
                                           float* __restrict__ dout) {
    __shared__ float smem[6688];   // 26,752 B
    int tid = threadIdx.x, lane = tid & 63, w = tid >> 6;
    int ml = lane & 15, q8 = lane >> 4;

    if (blockIdx.x < 16) {
        float (*red)[32][36] = (float(*)[32][36])smem;   // 4608 f
        int nb = blockIdx.x;
        int phase = 0;
        for (int s = 0; s < 3; s++) {
            {   // layer 1: hb[:, 32-col slice] = relu(concat @ W1 + b1) bf16
                const float* srcA = (w < 2) ? refined : (wmean + (size_t)s * 32 * 512 - 512);
                float iv0 = 1.f, iv1 = 1.f;
                if (w >= 2) {
                    iv0 = wsuminv[s * 32 + ml];
                    iv1 = wsuminv[s * 32 + 16 + ml];
                }
                int kw = w * 256;
                floatx4 acc[2][2];
#pragma unroll
                for (int mt = 0; mt < 2; mt++)
#pragma unroll
                    for (int nt = 0; nt < 2; nt++) acc[mt][nt] = (floatx4){0.f, 0.f, 0.f, 0.f};
                for (int st = 0; st < 8; st++) {
                    int k0 = kw + st * 32 + q8 * 8;
                    S8B8 a[2];
#pragma unroll
                    for (int mt = 0; mt < 2; mt++) {
                        float sc = mt ? iv1 : iv0;
                        const float* p = &srcA[(size_t)(mt * 16 + ml) * 512 + k0];
                        float4 f0 = *(const float4*)p;
                        float4 f1 = *(const float4*)(p + 4);
                        short8 t;
                        t[0] = f2bf(f0.x * sc); t[1] = f2bf(f0.y * sc);
                        t[2] = f2bf(f0.z * sc); t[3] = f2bf(f0.w * sc);
                        t[4] = f2bf(f1.x * sc); t[5] = f2bf(f1.y * sc);
                        t[6] = f2bf(f1.z * sc); t[7] = f2bf(f1.w * sc);
                        a[mt].s = t;
                    }
#pragma unroll
                    for (int nt = 0; nt < 2; nt++) {
                        int n = nb * 32 + nt * 16 + ml;
                        S8B8 b; b.s = *(const short8*)&W1p[((size_t)(k0 >> 3) * 512 + n) * 8];
#pragma unroll
                        for (int mt = 0; mt < 2; mt++)
                            acc[mt][nt] = __builtin_amdgcn_mfma_f32_16x16x32_bf16(a[mt].b, b.b, acc[mt][nt], 0, 0, 0);
                    }
                }
                __syncthreads();
#pragma unroll
                for (int mt = 0; mt < 2; mt++)
#pragma unroll
                    for (int nt = 0; nt < 2; nt++)
#pragma unroll
                        for (int r = 0; r < 4; r++)
                            red[w][mt * 16 + q8 * 4 + r][nt * 16 + ml] = acc[mt][nt][r];
                __syncthreads();
                int m = tid >> 3, n0 = (tid & 7) * 4;
                short4_t o;
#pragma unroll
                for (int i = 0; i < 4; i++) {
                    float v = b1[nb * 32 + n0 + i];
#pragma unroll
                    for (int w4 = 0; w4 < 4; w4++) v += red[w4][m][n0 + i];
                    o[i] = f2bf(fmaxf(v, 0.f));
                }
                *(short4_t*)&hb[(size_t)m * 512 + nb * 32 + n0] = o;
            }
            gbar(bar, phase++, 16);
            {   // layer 2: refined[:, slice] += 0.1*(hb @ W2 + b2)
                int kw = w * 128;
                floatx4 acc[2][2];
#pragma unroll
                for (int mt = 0; mt < 2; mt++)
#pragma unroll
                    for (int nt = 0; nt < 2; nt++) acc[mt][nt] = (floatx4){0.f, 0.f, 0.f, 0.f};
                for (int st = 0; st < 4; st++) {
                    int k0 = kw + st * 32 + q8 * 8;
                    S8B8 a[2];
#pragma unroll
                    for (int mt = 0; mt < 2; mt++)
                        a[mt].s = *(const short8*)&hb[(size_t)(mt * 16 + ml) * 512 + k0];
#pragma unroll
                    for (int nt = 0; nt < 2; nt++) {
                        int n = nb * 32 + nt * 16 + ml;
                        S8B8 b; b.s = *(const short8*)&W2p[((size_t)(k0 >> 3) * 512 + n) * 8];
#pragma unroll
                        for (int mt = 0; mt < 2; mt++)
                            acc[mt][nt] = __builtin_amdgcn_mfma_f32_16x16x32_bf16(a[mt].b, b.b, acc[mt][nt], 0, 0, 0);
                    }
                }
                __syncthreads();
#pragma unroll
                for (int mt = 0; mt < 2; mt++)
#pragma unroll
                    for (int nt = 0; nt < 2; nt++)
#pragma unroll
                        for (int r = 0; r < 4; r++)
                            red[w][mt * 16 + q8 * 4 + r][nt * 16 + ml] = acc[mt][nt][r];
                __syncthreads();
                int m = tid >> 3, n0 = (tid & 7) * 4;
#pragma unroll
                for (int i = 0; i < 4; i++) {
                    int c = nb * 32 + n0 + i;
                    float v = b2[c];
#pragma unroll
                    for (int w4 = 0; w4 < 4; w4++) v += red[w4][m][n0 + i];
                    float val = refined[(size_t)m * 512 + c] + 0.1f * v;
                    refined[(size_t)m * 512 + c] = val;
                    if (s == 2) dout[(size_t)m * 512 + c] = val;
                }
            }
            if (s < 2) gbar(bar, phase++, 16);
        }
    } else {
        // ---- confidence (R11 verbatim): block = 16q; thread = 2k x 1q ----
        short* hq_lds = (short*)smem;                  // [16][280] s = 8960 B
        short* hp_s   = (short*)smem + 4480;           // [32][260] s = 16640 B
        float* wc2s   = smem + 6400;                   // 256 f
        float* confl  = smem + 6656;                   // 32 f
        int q0 = (blockIdx.x - 16) * 16;

        wc2s[tid] = Wc2[tid];
        if (tid < 32) confl[tid] = 0.f;
#pragma unroll
        for (int i = 0; i < 8; i++) {                  // hp: 2048 float4 -> bf16 short4
            int idx = i * 256 + tid;
            int r = idx >> 6, c = (idx & 63) * 4;
            float4 v = *(const float4*)&hpb[r * 256 + c];
            short4_t o;
            o[0] = f2bf(v.x); o[1] = f2bf(v.y); o[2] = f2bf(v.z); o[3] = f2bf(v.w);
            *(short4_t*)&hp_s[r * 260 + c] = o;
        }
        {
            const short* hqs = hq_g + (size_t)q0 * 256;
            int r = tid >> 4, c = (tid & 15) * 16;
            *(short8*)&hq_lds[r * 280 + c] = *(const short8*)&hqs[r * 256 + c];
            *(short8*)&hq_lds[r * 280 + c + 8] = *(const short8*)&hqs[r * 256 + c + 8];
        }
        __syncthreads();

        int q = tid & 15, kg = tid >> 4;
        int k0 = kg, k1 = kg + 16;
        float s0 = 0.f, s1 = 0.f;
        for (int h = 0; h < 256; h += 4) {
            uint2 hv = *(uint2*)&hq_lds[q * 280 + h];
            float f0 = bflo(hv.x), f1 = bfhi(hv.x), f2 = bflo(hv.y), f3 = bfhi(hv.y);
            uint2 u0 = *(uint2*)&hp_s[k0 * 260 + h];
            uint2 u1 = *(uint2*)&hp_s[k1 * 260 + h];
            float4 wv = *(float4*)&wc2s[h];
            s0 += fmaxf(bflo(u0.x) + f0, 0.f) * wv.x;
            s0 += fmaxf(bfhi(u0.x) + f1, 0.f) * wv.y;
            s0 += fmaxf(bflo(u0.y) + f2, 0.f) * wv.z;
            s0 += fmaxf(bfhi(u0.y) + f3, 0.f) * wv.w;
            s1 += fmaxf(bflo(u1.x) + f0, 0.f) * wv.x;
            s1 += fmaxf(bfhi(u1.x) + f1, 0.f) * wv.y;
            s1 += fmaxf(bflo(u1.y) + f2, 0.f) * wv.z;
            s1 += fmaxf(bfhi(u1.y) + f3, 0.f) * wv.w;
        }
        float bc2 = bc2p[0];
        float v0 = 1.f / (1.f + __expf(-(s0 + bc2)));
        float v1 = 1.f / (1.f + __expf(-(s1 + bc2)));
        atomicAdd(&confl[k0], v0);
        atomicAdd(&confl[k1], v1);
        __syncthreads();
        if (tid < 32) atomicAdd(&dout[16384 + tid], confl[tid] * (1.0f / 16384.0f));
    }
}

extern "C" void kernel_launch(void* const* d_in, const int* in_sizes, int n_in,
                              void* d_out, int out_size, void* d_ws, size_t ws_size,
                              hipStream_t stream) {
    const float* proto = (const float*)d_in[0];
    const float* qf    = (const float*)d_in[1];
    const float* qd    = (const float*)d_in[2];
    const float* W1    = (const float*)d_in[3];
    const float* b1    = (const float*)d_in[4];
    const float* W2    = (const float*)d_in[5];
    const float* b2    = (const float*)d_in[6];
    const float* Wc1   = (const float*)d_in[7];
    const float* bc1   = (const float*)d_in[8];
    const float* Wc2   = (const float*)d_in[9];
    const float* bc2   = (const float*)d_in[10];
    float* out = (float*)d_out;

    float* ws = (float*)d_ws;
    short* softT   = (short*)ws;                 // 1,572,864 s
    short* qf2b    = (short*)(ws + 786432);      // 8,388,608 s
    float* wmean   = ws + 4980736;               // 49,152 f (raw accumulator)
    float* refined = ws + 5029888;               // 16,384 f
    short* hb      = (short*)(ws + 5046272);     // 16,384 s
    short* W1p     = (short*)(ws + 5054464);     // 524,288 s
    short* W2p     = (short*)(ws + 5316608);     // 262,144 s
    short* wqp     = (short*)(ws + 5447680);     // 131,072 s
    float* hpb     = ws + 5513216;               // 8,192 f
    int*   bar     = (int*)(ws + 5521408);       // 8 ints
    float* wsuminv = ws + 5521416;               // 96 f
    short* hq      = (short*)(ws + 5521536);     // 4,194,304 s

    k_A<<<5952, 256, 0, stream>>>(qd, W1, W2, Wc1, proto, qf, softT, W1p, W2p, wqp,
                                  refined, qf2b, wmean, bar, out);
    k_B<<<640, 256, 0, stream>>>(qf2b, softT, wqp, wmean, hq, wsuminv, proto, Wc1, bc1, hpb);
    k_D<<<1040, 256, 0, stream>>>(wmean, wsuminv, W1p, b1, W2p, b2, refined, hb, bar,
                                  hq, hpb, Wc2, bc2, out);
}